// Round 10
// baseline (199.262 us; speedup 1.0000x reference)
//
#include <hip/hip_runtime.h>
#include <hip/hip_bf16.h>

// ---------------------------------------------------------------------------
// FFT butterfly attention. delta = x_a^T P (x_a - x_b), P = scale*Wq*Wk^T
// (bf16, MFMA prep). w0 = sigmoid(delta); v' = mix(va, vb).
//
// Split design (r5-r9 verified): weights depend only on x/PT, never v.
//  * weights_all_kernel: both halves in ONE 2048-block dispatch, halves
//    INTERLEAVED even/odd (r10) so each CU's residency mixes 7- and 6-stage
//    blocks -> balanced tail. Body = r8's weights4 (2x2 wave tiling,
//    XOR-swizzled xb, 4 partials) + r9's PT double-buffer prefetch.
//    r10: staging bf16 conversion via v_cvt_pk_bf16_f32 (1 op / 2 values,
//    RNE == our manual f2bf bit-exactly) -- cuts ~110 VALU ops/thread
//    (VALUBusy measured 48%: VALU is real work, not stalls).
//  * mix_kernel (r8 verified): global distribute (L3 absorbs scatter),
//    register butterfly, LDS-staged swizzled coalesced store. r10: all
//    stage deltas hoisted ahead of the serial chain.
//  * tier-2 fallback (ws < 14.2MB): r5-verified weights2 + mix<NPART=2>.
//
// v register layout (pair-local): at stage u, lane L holds BOTH partners:
//   vlo = row ((L>>u)<<(u+1)) | (L & (2^u-1)),  vhi = vlo + 2^u
// (pair index of lane L == L; exchange partner lane L^2^u.)
// ---------------------------------------------------------------------------

typedef __bf16 bf16x8 __attribute__((ext_vector_type(8)));
typedef float  f32x4  __attribute__((ext_vector_type(4)));

#define XSTR 136                    // bf16/row, UNswizzled xb (prep + weights2)
#define XB_BYTES  (128 * XSTR * 2)  // 34816
#define PREP_LDS  (2 * XB_BYTES)    // 69632
#define LDS_W2    XB_BYTES          // weights2: unswizzled xb

#define XW 128                      // bf16/row, swizzled xb (weights_all)
#define LDS_W4    (128 * XW * 2)    // 32768

#define LDS_MIX   (128 * 128 * 4)   // 65536 (vbuf, swizzled)

// workspace layout
#define WS_DWT_OFF (512 * 1024)                      // PT in [0, 416K)
#define DWT4_BYTES (13 * 1024 * 4 * 64 * 4)          // 13.6 MB
#define WS_NEED4   (WS_DWT_OFF + DWT4_BYTES)

__device__ __forceinline__ float ubits(unsigned int u) {
    union { unsigned int u; float f; } v; v.u = u; return v.f;
}
__device__ __forceinline__ unsigned short f2bf(float f) {
    union { float f; unsigned int u; } v; v.f = f;
    unsigned int u = v.u;
    return (unsigned short)((u + 0x7fffu + ((u >> 16) & 1u)) >> 16);
}
// packed f32->bf16 RNE: D.lo = bf16(lo), D.hi = bf16(hi). Same rounding as f2bf.
__device__ __forceinline__ unsigned int cvtpk(float lo, float hi) {
    unsigned int r;
    asm("v_cvt_pk_bf16_f32 %0, %1, %2" : "=v"(r) : "v"(lo), "v"(hi));
    return r;
}
__device__ __forceinline__ int swzr(int r) { return ((r >> 1) ^ (r >> 2)) & 15; }

#define DPP_MOV_F(x, ctrl) \
    __int_as_float(__builtin_amdgcn_update_dpp(0, __float_as_int(x), (ctrl), 0xF, 0xF, true))

// cross-lane xor exchange with lane ^ (1<<u); u is compile-time-folded
__device__ __forceinline__ float xlane_u(float x, int u, int lane) {
    if (u == 0) return DPP_MOV_F(x, 0xB1);   // quad_perm xor1
    if (u == 1) return DPP_MOV_F(x, 0x4E);   // quad_perm xor2
    if (u == 2) return __int_as_float(__builtin_amdgcn_ds_swizzle(__float_as_int(x), 0x101F)); // xor4
    if (u == 3) return __int_as_float(__builtin_amdgcn_ds_swizzle(__float_as_int(x), 0x201F)); // xor8
    if (u == 4) return __int_as_float(__builtin_amdgcn_ds_swizzle(__float_as_int(x), 0x401F)); // xor16
    return __int_as_float(__builtin_amdgcn_ds_bpermute((lane ^ 32) << 2, __float_as_int(x))); // xor32
}

// ---------------- prep: PTf = fragment-major P^T -----------------------------
// frag (ci,kk) of 16-row tile ci at uint4 Pf[(ci*4+kk)*64 + lane]: 1KB coalesced.
__global__ __launch_bounds__(512)
void prep_kernel(const float* __restrict__ qkw, unsigned short* __restrict__ PT) {
    extern __shared__ char smem[];
    unsigned short* wkb = (unsigned short*)smem;              // A: Wk rows (n)
    unsigned short* wqb = (unsigned short*)(smem + XB_BYTES); // B: Wq rows (k)
    const int s = blockIdx.x;
    const float* Wq = qkw + (size_t)s * 32768;
    const float* Wk = Wq + 16384;
    const int tid = threadIdx.x;
    const int rl = tid >> 5, c4 = tid & 31;
#pragma unroll
    for (int j = 0; j < 8; ++j) {
        int r = j * 16 + rl;
        float4 vq = ((const float4*)Wq)[r * 32 + c4];
        float4 vk = ((const float4*)Wk)[r * 32 + c4];
        uint2 uq; uq.x = cvtpk(vq.x, vq.y); uq.y = cvtpk(vq.z, vq.w);
        uint2 uk; uk.x = cvtpk(vk.x, vk.y); uk.y = cvtpk(vk.z, vk.w);
        *(uint2*)(wqb + r * XSTR + c4 * 4) = uq;
        *(uint2*)(wkb + r * XSTR + c4 * 4) = uk;
    }
    __syncthreads();
    const int lane = tid & 63, w = tid >> 6;
    const int lane15 = lane & 15, quad = lane >> 4;
    f32x4 acc[8] = {};
#pragma unroll
    for (int kk = 0; kk < 4; ++kk) {
        bf16x8 a = *(const bf16x8*)(wkb + (w * 16 + lane15) * XSTR + kk * 32 + quad * 8);
#pragma unroll
        for (int ct = 0; ct < 8; ++ct) {
            bf16x8 b = *(const bf16x8*)(wqb + (ct * 16 + lane15) * XSTR + kk * 32 + quad * 8);
            acc[ct] = __builtin_amdgcn_mfma_f32_16x16x32_bf16(a, b, acc[ct], 0, 0, 0);
        }
    }
    // acc[ct][r] = PT[n][k], n = w*16 + quad*4 + r, k = ct*16 + lane15
    unsigned short* dst = PT + s * 16384;
#pragma unroll
    for (int ct = 0; ct < 8; ++ct) {
        const int kkf = ct >> 1;
        const int qf  = (ct & 1) * 2 + (lane15 >> 3);
        const int e   = lane15 & 7;
#pragma unroll
        for (int r = 0; r < 4; ++r) {
            int fi = (w * 4 + kkf) * 64 + qf * 16 + quad * 4 + r;
            dst[fi * 8 + e] = f2bf(acc[ct][r] * 0.17677669529663687f);
        }
    }
}

// ---------------- staging helpers -------------------------------------------
__device__ __forceinline__ void stage_xb(unsigned short* xb, const float* xsrc,
                                         int tid, int base, int h_off, int rstride) {
    const int rl = tid >> 5, c4 = tid & 31;
#pragma unroll
    for (int j = 0; j < 8; ++j) {
        int i  = j * 16 + rl;
        int gp = base + (i >> 6) * h_off + (i & 63) * rstride;
        float4 val = ((const float4*)xsrc)[gp * 32 + c4];
        ushort4 us; us.x = f2bf(val.x); us.y = f2bf(val.y);
        us.z = f2bf(val.z); us.w = f2bf(val.w);
        *(ushort4*)(xb + i * XSTR + c4 * 4) = us;
    }
}

// swizzled: row i, 16B slot s lives at byte i*256 + ((s ^ swzr(i))*16)
__device__ __forceinline__ void stage_xb_swz(unsigned short* xb, const float* xsrc,
                                             int tid, int base, int h_off, int rstride) {
    const int rl = tid >> 5, c4 = tid & 31;
#pragma unroll
    for (int j = 0; j < 8; ++j) {
        int i  = j * 16 + rl;
        int gp = base + (i >> 6) * h_off + (i & 63) * rstride;
        float4 val = ((const float4*)xsrc)[gp * 32 + c4];
        uint2 us; us.x = cvtpk(val.x, val.y); us.y = cvtpk(val.z, val.w);
        int slot = c4 >> 1, half = c4 & 1;
        *(uint2*)(xb + i * XW + (((slot ^ swzr(i)) << 3) + half * 4)) = us;
    }
}

// ---------------- weights body: 2x2 tiling, swizzled xb, PT dbuf prefetch ----
template<int NS>
__device__ __forceinline__ void weights_body(const float* __restrict__ xsrc,
                                             const unsigned short* __restrict__ PT,
                                             float* __restrict__ dwt,
                                             unsigned short* xb, int tid, int bid,
                                             int s0, int base_mul, int h_off, int rstride)
{
    const int b    = bid >> 6;
    const int sub  = bid & 63;
    const int base = b * 8192 + sub * base_mul;

    stage_xb_swz(xb, xsrc, tid, base, h_off, rstride);

    const int lane = tid & 63, w = tid >> 6;
    const int lane15 = lane & 15, quad = lane >> 4;
    const int dh = w >> 1;            // dim-slice: dims dh*32..+31
    const int ph = w & 1;             // pair-slice: pairs ph*32..+31

    // ---- prologue: prefetch stage-0 A-frags (overlaps staging-wait) ----
    uint4 af[2][2][4];
    {
        const uint4* Pf = (const uint4*)PT + (size_t)s0 * 2048;
#pragma unroll
        for (int mt = 0; mt < 2; ++mt)
#pragma unroll
            for (int kk = 0; kk < 4; ++kk)
                af[0][mt][kk] = Pf[((dh * 2 + mt) * 4 + kk) * 64 + lane];
    }
    __syncthreads();   // xb ready; NO further barriers (xb read-only below)

#pragma unroll
    for (int u = 0; u < NS; ++u) {
        const int cur = u & 1, nxt = cur ^ 1;   // compile-time (full unroll)
        const int t   = 1 << u;
        const int tm1 = t - 1;

        // ---- prefetch next stage's A-frags; drain under MFMA + dot ----
        if (u + 1 < NS) {
            const uint4* Pf = (const uint4*)PT + (size_t)(s0 + u + 1) * 2048;
#pragma unroll
            for (int mt = 0; mt < 2; ++mt)
#pragma unroll
                for (int kk = 0; kk < 4; ++kk)
                    af[nxt][mt][kk] = Pf[((dh * 2 + mt) * 4 + kk) * 64 + lane];
        }

        // ---- Gt subtile: dims dh*32..+31 (C rows), pairs ph*32..+31 (C cols)
        f32x4 acc[2][2] = {};
#pragma unroll
        for (int pg = 0; pg < 2; ++pg) {
            const int p  = (ph * 2 + pg) * 16 + lane15;
            const int ar = ((p & ~tm1) << 1) | (p & tm1);
            const int swa = swzr(ar);
            const unsigned short* brow = xb + ar * XW;
#pragma unroll
            for (int kk = 0; kk < 4; ++kk) {
                bf16x8 bfrag = *(const bf16x8*)(brow + (((kk * 4 + quad) ^ swa) << 3));
#pragma unroll
                for (int mt = 0; mt < 2; ++mt) {
                    union { uint4 u; bf16x8 b; } av; av.u = af[cur][mt][kk];
                    acc[mt][pg] = __builtin_amdgcn_mfma_f32_16x16x32_bf16(av.b, bfrag, acc[mt][pg], 0, 0, 0);
                }
            }
        }

        // ---- partial dot over dims dh*32..+31; quad-reduce xor16+xor32 ----
        float sm[2];
#pragma unroll
        for (int pg = 0; pg < 2; ++pg) {
            const int p  = (ph * 2 + pg) * 16 + lane15;
            const int ar = ((p & ~tm1) << 1) | (p & tm1);
            const int br = ar + t;
            const int swa = swzr(ar), swb = swzr(br);
            float s = 0.f;
#pragma unroll
            for (int mt = 0; mt < 2; ++mt) {
                const int slot = dh * 4 + mt * 2 + (quad >> 1);
                uint2 ua = *(const uint2*)(xb + ar * XW + (((slot ^ swa) << 3) + (quad & 1) * 4));
                uint2 ub = *(const uint2*)(xb + br * XW + (((slot ^ swb) << 3) + (quad & 1) * 4));
                float a0 = ubits(ua.x << 16), a1 = ubits(ua.x & 0xffff0000u);
                float a2 = ubits(ua.y << 16), a3 = ubits(ua.y & 0xffff0000u);
                float b0 = ubits(ub.x << 16), b1 = ubits(ub.x & 0xffff0000u);
                float b2 = ubits(ub.y << 16), b3 = ubits(ub.y & 0xffff0000u);
                s += acc[mt][pg][0] * (a0 - b0) + acc[mt][pg][1] * (a1 - b1)
                   + acc[mt][pg][2] * (a2 - b2) + acc[mt][pg][3] * (a3 - b3);
            }
            s += xlane_u(s, 4, lane);
            s += xlane_u(s, 5, lane);
            sm[pg] = s;
        }
        // lanes 0..31 store pairs ph*32 + (lane&31), partial dh (coalesced 128B)
        float v = (lane & 16) ? sm[1] : sm[0];
        if (lane < 32)
            dwt[(((size_t)(s0 + u) * 1024 + bid) * 4 + dh) * 64 + ph * 32 + (lane & 31)] = v;
    }
}

// one dispatch, both halves INTERLEAVED even/odd for tail balance
__global__ __launch_bounds__(512, 4)
void weights_all_kernel(const float* __restrict__ xsrc,
                        const unsigned short* __restrict__ PT,
                        float* __restrict__ dwt)
{
    extern __shared__ char smem[];
    unsigned short* xb = (unsigned short*)smem;   // swizzled [128][XW]
    const int tid = threadIdx.x;
    const int bid = blockIdx.x >> 1;
    if ((blockIdx.x & 1) == 0) {
        weights_body<7>(xsrc, PT, dwt, xb, tid, bid,
                        /*s0=*/0, /*base_mul=*/128, /*h_off=*/64, /*rstride=*/1);
    } else {
        weights_body<6>(xsrc, PT, dwt, xb, tid, bid,
                        /*s0=*/7, /*base_mul=*/2, /*h_off=*/1, /*rstride=*/128);
    }
}

// ---------------- weights2: r5-verified fallback (2 partials) ----------------
template<int NS>
__global__ __launch_bounds__(512, 4)
void weights2_kernel(const float* __restrict__ xsrc,
                     const unsigned short* __restrict__ PT,
                     float* __restrict__ dwt,
                     int s0, int base_mul, int h_off, int rstride)
{
    extern __shared__ char smem[];
    unsigned short* xb = (unsigned short*)smem;

    const int tid  = threadIdx.x;
    const int b    = blockIdx.x >> 6;
    const int sub  = blockIdx.x & 63;
    const int base = b * 8192 + sub * base_mul;

    stage_xb(xb, xsrc, tid, base, h_off, rstride);

    const int lane = tid & 63, w = tid >> 6;
    const int lane15 = lane & 15, quad = lane >> 4;
    const int nt = w & 3;
    const int mh = w >> 2;
    const int p  = nt * 16 + lane15;

    __syncthreads();

#pragma unroll
    for (int u = 0; u < NS; ++u) {
        const int t   = 1 << u;
        const int tm1 = t - 1;
        const int ar  = ((p & ~tm1) << 1) | (p & tm1);

        float sm = 0.f;
        {
            const uint4* Pf = (const uint4*)PT + (size_t)(s0 + u) * 2048;
            const unsigned short* brow = xb + ar * XSTR + quad * 8;
            f32x4 acc[4] = {};
#pragma unroll
            for (int kk = 0; kk < 4; ++kk) {
                bf16x8 bfrag = *(const bf16x8*)(brow + kk * 32);
#pragma unroll
                for (int mt = 0; mt < 4; ++mt) {
                    union { uint4 u; bf16x8 b; } av;
                    av.u = Pf[((mh * 4 + mt) * 4 + kk) * 64 + lane];
                    acc[mt] = __builtin_amdgcn_mfma_f32_16x16x32_bf16(av.b, bfrag, acc[mt], 0, 0, 0);
                }
            }
            const unsigned short* da = xb + ar * XSTR + mh * 64 + quad * 4;
            const unsigned short* db = da + t * XSTR;
#pragma unroll
            for (int mt = 0; mt < 4; ++mt) {
                uint2 ua = *(const uint2*)(da + mt * 16);
                uint2 ub = *(const uint2*)(db + mt * 16);
                float a0 = ubits(ua.x << 16), a1 = ubits(ua.x & 0xffff0000u);
                float a2 = ubits(ua.y << 16), a3 = ubits(ua.y & 0xffff0000u);
                float b0 = ubits(ub.x << 16), b1 = ubits(ub.x & 0xffff0000u);
                float b2 = ubits(ub.y << 16), b3 = ubits(ub.y & 0xffff0000u);
                sm += acc[mt][0] * (a0 - b0) + acc[mt][1] * (a1 - b1)
                    + acc[mt][2] * (a2 - b2) + acc[mt][3] * (a3 - b3);
            }
        }
        sm += xlane_u(sm, 4, lane);
        sm += xlane_u(sm, 5, lane);
        if (lane < 16)
            dwt[((size_t)(s0 + u) * 1024 + blockIdx.x) * 128 + mh * 64 + nt * 16 + lane] = sm;
    }
}

// ---------------- mix: global distribute, LDS-staged coalesced store ---------
template<int NS, int NPART>
__global__ __launch_bounds__(512, 4)
void mix_kernel(const float* __restrict__ vsrc,
                float* __restrict__ vdst,
                const float* __restrict__ dwt,
                int s0, int base_mul, int h_off, int rstride)
{
    extern __shared__ char smem[];
    float* vbuf = (float*)smem;   // [128][128], 16B slots XOR'd by (row&31)

    const int tid  = threadIdx.x;
    const int b    = blockIdx.x >> 6;
    const int sub  = blockIdx.x & 63;
    const int base = b * 8192 + sub * base_mul;
    const int lane = tid & 63, w = tid >> 6;
    const int rl = tid >> 5, c4 = tid & 31;

    // ---- hoist ALL stage deltas ahead of the serial chain ----
    float dlt[NS];
#pragma unroll
    for (int u = 0; u < NS; ++u) {
        const float* dw = dwt + ((size_t)(s0 + u) * 1024 + blockIdx.x) * (NPART * 64);
        float d = 0.f;
#pragma unroll
        for (int k = 0; k < NPART; ++k) d += dw[k * 64 + lane];
        dlt[u] = d;
    }

    // ---- distribute directly from global (r5-verified path; L3 absorbs) ----
    float vlo[16], vhi[16];
    {
        int r0 = 2 * lane, r1 = r0 + 1;
        int gp0 = base + (r0 >> 6) * h_off + (r0 & 63) * rstride;
        int gp1 = base + (r1 >> 6) * h_off + (r1 & 63) * rstride;
        const float* p0 = vsrc + (size_t)gp0 * 128 + w * 16;
        const float* p1 = vsrc + (size_t)gp1 * 128 + w * 16;
#pragma unroll
        for (int j = 0; j < 4; ++j) {
            float4 a = ((const float4*)p0)[j];
            float4 c = ((const float4*)p1)[j];
            vlo[4*j] = a.x; vlo[4*j+1] = a.y; vlo[4*j+2] = a.z; vlo[4*j+3] = a.w;
            vhi[4*j] = c.x; vhi[4*j+1] = c.y; vhi[4*j+2] = c.z; vhi[4*j+3] = c.w;
        }
    }

#pragma unroll
    for (int u = 0; u < NS; ++u) {
        const float w0 = 1.0f / (1.0f + __expf(-dlt[u]));
        if (u < NS - 1) {
            const bool isE = ((lane >> u) & 1) == 0;
            const float wk = isE ? w0 : 1.0f - w0;
#pragma unroll
            for (int j = 0; j < 16; ++j) {
                float a = vlo[j], c = vhi[j];
                float s    = a + c;
                float keep = c + wk * (a - c);   // E: out_a ; O: out_b
                float send = s - keep;           // E: out_b ; O: out_a
                float ex   = xlane_u(send, u, lane);
                vlo[j] = isE ? keep : ex;
                vhi[j] = isE ? ex : keep;
            }
        } else {
            const float w1 = 1.0f - w0;
#pragma unroll
            for (int j = 0; j < 16; ++j) {
                float a = vlo[j], c = vhi[j];
                float oa = w0 * a + w1 * c;
                vlo[j] = oa;
                vhi[j] = a + c - oa;
            }
        }
    }

    // ---- write registers to swizzled vbuf (final-stage layout) ----
    {
        const int FU = NS - 1;
        int r0 = ((lane >> FU) << (FU + 1)) | (lane & ((1 << FU) - 1));
        int r1 = r0 + (1 << FU);
#pragma unroll
        for (int j = 0; j < 4; ++j) {
            float4 a; a.x = vlo[4*j]; a.y = vlo[4*j+1]; a.z = vlo[4*j+2]; a.w = vlo[4*j+3];
            float4 c; c.x = vhi[4*j]; c.y = vhi[4*j+1]; c.z = vhi[4*j+2]; c.w = vhi[4*j+3];
            int slot = w * 4 + j;
            *(float4*)(vbuf + r0 * 128 + ((slot ^ (r0 & 31)) << 2)) = a;
            *(float4*)(vbuf + r1 * 128 + ((slot ^ (r1 & 31)) << 2)) = c;
        }
    }
    __syncthreads();

    // ---- coalesced store vbuf -> vdst ----
#pragma unroll
    for (int j = 0; j < 8; ++j) {
        int i  = j * 16 + rl;
        int gp = base + (i >> 6) * h_off + (i & 63) * rstride;
        ((float4*)vdst)[gp * 32 + c4] =
            *(const float4*)(vbuf + i * 128 + (((c4 ^ (i & 31)) << 2)));
    }
}

extern "C" void kernel_launch(void* const* d_in, const int* in_sizes, int n_in,
                              void* d_out, int out_size, void* d_ws, size_t ws_size,
                              hipStream_t stream) {
    const float* x   = (const float*)d_in[0];
    const float* qkw = (const float*)d_in[1];
    float* out = (float*)d_out;
    unsigned short* PT = (unsigned short*)d_ws;   // 13*16384 bf16 = 416 KB
    float* dwt = (float*)((char*)d_ws + WS_DWT_OFF);

    (void)hipFuncSetAttribute((const void*)prep_kernel,
                              hipFuncAttributeMaxDynamicSharedMemorySize, PREP_LDS);

    prep_kernel<<<13, 512, PREP_LDS, stream>>>(qkw, PT);

    if (ws_size >= (size_t)WS_NEED4) {
        (void)hipFuncSetAttribute((const void*)weights_all_kernel,
                                  hipFuncAttributeMaxDynamicSharedMemorySize, LDS_W4);
        (void)hipFuncSetAttribute((const void*)mix_kernel<7,4>,
                                  hipFuncAttributeMaxDynamicSharedMemorySize, LDS_MIX);
        (void)hipFuncSetAttribute((const void*)mix_kernel<6,4>,
                                  hipFuncAttributeMaxDynamicSharedMemorySize, LDS_MIX);

        // both weights halves in one dispatch (independent of mix chain)
        weights_all_kernel<<<2048, 512, LDS_W4, stream>>>(x, PT, dwt);

        // stages 0..6: contiguous 128-position blocks
        mix_kernel<7,4><<<1024, 512, LDS_MIX, stream>>>(
            x, out, dwt, /*s0=*/0, /*base_mul=*/128, /*h_off=*/64, /*rstride=*/1);
        // stages 7..12: 2 lo x 64 hi (stride 128); in-place on d_out
        mix_kernel<6,4><<<1024, 512, LDS_MIX, stream>>>(
            out, out, dwt, /*s0=*/7, /*base_mul=*/2, /*h_off=*/1, /*rstride=*/128);
    } else {
        // tier-2: r5-verified weights2 (dwt 6.8MB) + mix<NPART=2>
        (void)hipFuncSetAttribute((const void*)weights2_kernel<7>,
                                  hipFuncAttributeMaxDynamicSharedMemorySize, LDS_W2);
        (void)hipFuncSetAttribute((const void*)weights2_kernel<6>,
                                  hipFuncAttributeMaxDynamicSharedMemorySize, LDS_W2);
        (void)hipFuncSetAttribute((const void*)mix_kernel<7,2>,
                                  hipFuncAttributeMaxDynamicSharedMemorySize, LDS_MIX);
        (void)hipFuncSetAttribute((const void*)mix_kernel<6,2>,
                                  hipFuncAttributeMaxDynamicSharedMemorySize, LDS_MIX);

        weights2_kernel<7><<<1024, 512, LDS_W2, stream>>>(
            x, PT, dwt, 0, 128, 64, 1);
        mix_kernel<7,2><<<1024, 512, LDS_MIX, stream>>>(
            x, out, dwt, 0, 128, 64, 1);
        weights2_kernel<6><<<1024, 512, LDS_W2, stream>>>(
            x, PT, dwt, 7, 2, 1, 128);
        mix_kernel<6,2><<<1024, 512, LDS_MIX, stream>>>(
            out, out, dwt, 7, 2, 1, 128);
    }
}

// Round 11
// 197.227 us; speedup vs baseline: 1.0103x; 1.0103x over previous
//
#include <hip/hip_runtime.h>
#include <hip/hip_bf16.h>

// ---------------------------------------------------------------------------
// FFT butterfly attention. delta = x_a^T P (x_a - x_b), P = scale*Wq*Wk^T
// (bf16, MFMA prep). w0 = sigmoid(delta); v' = mix(va, vb).
//
// r11: FUSED weights+mix per half. Key fact: weights block bid computes
// deltas for exactly the 128 rows mix block bid consumes -> pass wt through
// LDS (7KB) instead of dwt through global (13.6MB round-trip + one dispatch
// boundary, ~10us/boundary measured as ~40us total gaps in r9/r10).
//  * weights phase = r9-verified body: 2x2 wave tiling (dh=w>>1 dims,
//    ph=w&1 pairs), XOR-swizzled xb, PT double-buffer prefetch, cvt_pk
//    staging (kept: VALUBusy 48->40 in r10). Interleave REVERTED (cost
//    +7us in r10: destroyed co-dispatched blocks' L2 locality).
//  * one barrier, then mix phase: vlo/vhi loaded from global AFTER the
//    weights phase (phase-disjoint register lifetimes: live-set is
//    max(~70,~45), not sum -> no r2/r4 spill at cap 128).
//  * store: reuse dead xb as 64-row staging buffer, two passes ->
//    coalesced float4 stores (r5 measured x1.92 write inflation without).
// LDS 32K xb + 7K wt = 39.9K -> 4 blocks/CU. Launches: prep, fused7, fused6.
//
// v register layout (pair-local): at stage u, lane L holds BOTH partners:
//   vlo = row ((L>>u)<<(u+1)) | (L & (2^u-1)),  vhi = vlo + 2^u
// (pair index of lane L == L; exchange partner lane L^2^u.)
// ---------------------------------------------------------------------------

typedef __bf16 bf16x8 __attribute__((ext_vector_type(8)));
typedef float  f32x4  __attribute__((ext_vector_type(4)));

#define XSTR 136                    // bf16/row, UNswizzled (prep only)
#define XB_BYTES  (128 * XSTR * 2)  // 34816
#define PREP_LDS  (2 * XB_BYTES)    // 69632

#define XW 128                      // bf16/row, swizzled xb
#define XB_SWZ    (128 * XW * 2)    // 32768
#define WT_LDS_OFF XB_SWZ
#define LDS_FUSED (XB_SWZ + 7 * 4 * 64 * 4)   // 39936 -> 4 blocks/CU

__device__ __forceinline__ float ubits(unsigned int u) {
    union { unsigned int u; float f; } v; v.u = u; return v.f;
}
__device__ __forceinline__ unsigned short f2bf(float f) {
    union { float f; unsigned int u; } v; v.f = f;
    unsigned int u = v.u;
    return (unsigned short)((u + 0x7fffu + ((u >> 16) & 1u)) >> 16);
}
// packed f32->bf16 RNE: D.lo = bf16(lo), D.hi = bf16(hi). Same rounding as f2bf.
__device__ __forceinline__ unsigned int cvtpk(float lo, float hi) {
    unsigned int r;
    asm("v_cvt_pk_bf16_f32 %0, %1, %2" : "=v"(r) : "v"(lo), "v"(hi));
    return r;
}
__device__ __forceinline__ int swzr(int r) { return ((r >> 1) ^ (r >> 2)) & 15; }

#define DPP_MOV_F(x, ctrl) \
    __int_as_float(__builtin_amdgcn_update_dpp(0, __float_as_int(x), (ctrl), 0xF, 0xF, true))

// cross-lane xor exchange with lane ^ (1<<u); u is compile-time-folded
__device__ __forceinline__ float xlane_u(float x, int u, int lane) {
    if (u == 0) return DPP_MOV_F(x, 0xB1);   // quad_perm xor1
    if (u == 1) return DPP_MOV_F(x, 0x4E);   // quad_perm xor2
    if (u == 2) return __int_as_float(__builtin_amdgcn_ds_swizzle(__float_as_int(x), 0x101F)); // xor4
    if (u == 3) return __int_as_float(__builtin_amdgcn_ds_swizzle(__float_as_int(x), 0x201F)); // xor8
    if (u == 4) return __int_as_float(__builtin_amdgcn_ds_swizzle(__float_as_int(x), 0x401F)); // xor16
    return __int_as_float(__builtin_amdgcn_ds_bpermute((lane ^ 32) << 2, __float_as_int(x))); // xor32
}

// ---------------- prep: PTf = fragment-major P^T -----------------------------
// frag (ci,kk) of 16-row tile ci at uint4 Pf[(ci*4+kk)*64 + lane]: 1KB coalesced.
__global__ __launch_bounds__(512)
void prep_kernel(const float* __restrict__ qkw, unsigned short* __restrict__ PT) {
    extern __shared__ char smem[];
    unsigned short* wkb = (unsigned short*)smem;              // A: Wk rows (n)
    unsigned short* wqb = (unsigned short*)(smem + XB_BYTES); // B: Wq rows (k)
    const int s = blockIdx.x;
    const float* Wq = qkw + (size_t)s * 32768;
    const float* Wk = Wq + 16384;
    const int tid = threadIdx.x;
    const int rl = tid >> 5, c4 = tid & 31;
#pragma unroll
    for (int j = 0; j < 8; ++j) {
        int r = j * 16 + rl;
        float4 vq = ((const float4*)Wq)[r * 32 + c4];
        float4 vk = ((const float4*)Wk)[r * 32 + c4];
        uint2 uq; uq.x = cvtpk(vq.x, vq.y); uq.y = cvtpk(vq.z, vq.w);
        uint2 uk; uk.x = cvtpk(vk.x, vk.y); uk.y = cvtpk(vk.z, vk.w);
        *(uint2*)(wqb + r * XSTR + c4 * 4) = uq;
        *(uint2*)(wkb + r * XSTR + c4 * 4) = uk;
    }
    __syncthreads();
    const int lane = tid & 63, w = tid >> 6;
    const int lane15 = lane & 15, quad = lane >> 4;
    f32x4 acc[8] = {};
#pragma unroll
    for (int kk = 0; kk < 4; ++kk) {
        bf16x8 a = *(const bf16x8*)(wkb + (w * 16 + lane15) * XSTR + kk * 32 + quad * 8);
#pragma unroll
        for (int ct = 0; ct < 8; ++ct) {
            bf16x8 b = *(const bf16x8*)(wqb + (ct * 16 + lane15) * XSTR + kk * 32 + quad * 8);
            acc[ct] = __builtin_amdgcn_mfma_f32_16x16x32_bf16(a, b, acc[ct], 0, 0, 0);
        }
    }
    // acc[ct][r] = PT[n][k], n = w*16 + quad*4 + r, k = ct*16 + lane15
    unsigned short* dst = PT + s * 16384;
#pragma unroll
    for (int ct = 0; ct < 8; ++ct) {
        const int kkf = ct >> 1;
        const int qf  = (ct & 1) * 2 + (lane15 >> 3);
        const int e   = lane15 & 7;
#pragma unroll
        for (int r = 0; r < 4; ++r) {
            int fi = (w * 4 + kkf) * 64 + qf * 16 + quad * 4 + r;
            dst[fi * 8 + e] = f2bf(acc[ct][r] * 0.17677669529663687f);
        }
    }
}

// swizzled staging: row i, 16B slot s lives at byte i*256 + ((s ^ swzr(i))*16)
__device__ __forceinline__ void stage_xb_swz(unsigned short* xb, const float* xsrc,
                                             int tid, int base, int h_off, int rstride) {
    const int rl = tid >> 5, c4 = tid & 31;
#pragma unroll
    for (int j = 0; j < 8; ++j) {
        int i  = j * 16 + rl;
        int gp = base + (i >> 6) * h_off + (i & 63) * rstride;
        float4 val = ((const float4*)xsrc)[gp * 32 + c4];
        uint2 us; us.x = cvtpk(val.x, val.y); us.y = cvtpk(val.z, val.w);
        int slot = c4 >> 1, half = c4 & 1;
        *(uint2*)(xb + i * XW + (((slot ^ swzr(i)) << 3) + half * 4)) = us;
    }
}

// ---------------- fused: weights phase -> LDS wt -> mix phase ----------------
template<int NS>
__global__ __launch_bounds__(512, 4)
void fused_kernel(const float* __restrict__ xsrc,
                  const float* __restrict__ vsrc,
                  float* __restrict__ vdst,
                  const unsigned short* __restrict__ PT,
                  int s0, int base_mul, int h_off, int rstride)
{
    extern __shared__ char smem[];
    unsigned short* xb  = (unsigned short*)smem;            // [128][XW] swizzled
    float*          wtl = (float*)(smem + WT_LDS_OFF);      // [NS][4][64]

    const int tid  = threadIdx.x;
    const int b    = blockIdx.x >> 6;
    const int sub  = blockIdx.x & 63;
    const int base = b * 8192 + sub * base_mul;

    stage_xb_swz(xb, xsrc, tid, base, h_off, rstride);

    const int lane = tid & 63, w = tid >> 6;
    const int lane15 = lane & 15, quad = lane >> 4;
    const int dh = w >> 1;            // dim-slice: dims dh*32..+31
    const int ph = w & 1;             // pair-slice: pairs ph*32..+31

    // ---- prologue: prefetch stage-0 A-frags (overlaps staging-wait) ----
    uint4 af[2][2][4];
    {
        const uint4* Pf = (const uint4*)PT + (size_t)s0 * 2048;
#pragma unroll
        for (int mt = 0; mt < 2; ++mt)
#pragma unroll
            for (int kk = 0; kk < 4; ++kk)
                af[0][mt][kk] = Pf[((dh * 2 + mt) * 4 + kk) * 64 + lane];
    }
    __syncthreads();   // xb ready

    // ================= weights phase (no barriers inside) ===================
#pragma unroll
    for (int u = 0; u < NS; ++u) {
        const int cur = u & 1, nxt = cur ^ 1;   // compile-time (full unroll)
        const int t   = 1 << u;
        const int tm1 = t - 1;

        // prefetch next stage's A-frags; drain under MFMA + dot
        if (u + 1 < NS) {
            const uint4* Pf = (const uint4*)PT + (size_t)(s0 + u + 1) * 2048;
#pragma unroll
            for (int mt = 0; mt < 2; ++mt)
#pragma unroll
                for (int kk = 0; kk < 4; ++kk)
                    af[nxt][mt][kk] = Pf[((dh * 2 + mt) * 4 + kk) * 64 + lane];
        }

        // Gt subtile: dims dh*32..+31 (C rows), pairs ph*32..+31 (C cols)
        f32x4 acc[2][2] = {};
#pragma unroll
        for (int pg = 0; pg < 2; ++pg) {
            const int p  = (ph * 2 + pg) * 16 + lane15;
            const int ar = ((p & ~tm1) << 1) | (p & tm1);
            const int swa = swzr(ar);
            const unsigned short* brow = xb + ar * XW;
#pragma unroll
            for (int kk = 0; kk < 4; ++kk) {
                bf16x8 bfrag = *(const bf16x8*)(brow + (((kk * 4 + quad) ^ swa) << 3));
#pragma unroll
                for (int mt = 0; mt < 2; ++mt) {
                    union { uint4 u; bf16x8 b; } av; av.u = af[cur][mt][kk];
                    acc[mt][pg] = __builtin_amdgcn_mfma_f32_16x16x32_bf16(av.b, bfrag, acc[mt][pg], 0, 0, 0);
                }
            }
        }

        // partial dot over dims dh*32..+31; quad-reduce xor16+xor32
        float sm[2];
#pragma unroll
        for (int pg = 0; pg < 2; ++pg) {
            const int p  = (ph * 2 + pg) * 16 + lane15;
            const int ar = ((p & ~tm1) << 1) | (p & tm1);
            const int br = ar + t;
            const int swa = swzr(ar), swb = swzr(br);
            float s = 0.f;
#pragma unroll
            for (int mt = 0; mt < 2; ++mt) {
                const int slot = dh * 4 + mt * 2 + (quad >> 1);
                uint2 ua = *(const uint2*)(xb + ar * XW + (((slot ^ swa) << 3) + (quad & 1) * 4));
                uint2 ub = *(const uint2*)(xb + br * XW + (((slot ^ swb) << 3) + (quad & 1) * 4));
                float a0 = ubits(ua.x << 16), a1 = ubits(ua.x & 0xffff0000u);
                float a2 = ubits(ua.y << 16), a3 = ubits(ua.y & 0xffff0000u);
                float b0 = ubits(ub.x << 16), b1 = ubits(ub.x & 0xffff0000u);
                float b2 = ubits(ub.y << 16), b3 = ubits(ub.y & 0xffff0000u);
                s += acc[mt][pg][0] * (a0 - b0) + acc[mt][pg][1] * (a1 - b1)
                   + acc[mt][pg][2] * (a2 - b2) + acc[mt][pg][3] * (a3 - b3);
            }
            s += xlane_u(s, 4, lane);
            s += xlane_u(s, 5, lane);
            sm[pg] = s;
        }
        float v = (lane & 16) ? sm[1] : sm[0];
        if (lane < 32)
            wtl[(u * 4 + dh) * 64 + ph * 32 + (lane & 31)] = v;
    }
    __syncthreads();   // wt ready; all xb reads done (xb reusable below)

    // ================= mix phase ============================================
    // deltas: sum 4 dh-partials per stage (2-way LDS reads, free)
    float dlt[NS];
#pragma unroll
    for (int u = 0; u < NS; ++u) {
        dlt[u] = wtl[(u * 4 + 0) * 64 + lane] + wtl[(u * 4 + 1) * 64 + lane]
               + wtl[(u * 4 + 2) * 64 + lane] + wtl[(u * 4 + 3) * 64 + lane];
    }

    // distribute v from global (loaded AFTER weights phase: no reg overlap)
    float vlo[16], vhi[16];
    {
        int r0 = 2 * lane, r1 = r0 + 1;
        int gp0 = base + (r0 >> 6) * h_off + (r0 & 63) * rstride;
        int gp1 = base + (r1 >> 6) * h_off + (r1 & 63) * rstride;
        const float* p0 = vsrc + (size_t)gp0 * 128 + w * 16;
        const float* p1 = vsrc + (size_t)gp1 * 128 + w * 16;
#pragma unroll
        for (int j = 0; j < 4; ++j) {
            float4 a = ((const float4*)p0)[j];
            float4 c = ((const float4*)p1)[j];
            vlo[4*j] = a.x; vlo[4*j+1] = a.y; vlo[4*j+2] = a.z; vlo[4*j+3] = a.w;
            vhi[4*j] = c.x; vhi[4*j+1] = c.y; vhi[4*j+2] = c.z; vhi[4*j+3] = c.w;
        }
    }

#pragma unroll
    for (int u = 0; u < NS; ++u) {
        const float w0 = 1.0f / (1.0f + __expf(-dlt[u]));
        if (u < NS - 1) {
            const bool isE = ((lane >> u) & 1) == 0;
            const float wk = isE ? w0 : 1.0f - w0;
#pragma unroll
            for (int j = 0; j < 16; ++j) {
                float a = vlo[j], c = vhi[j];
                float s    = a + c;
                float keep = c + wk * (a - c);   // E: out_a ; O: out_b
                float send = s - keep;           // E: out_b ; O: out_a
                float ex   = xlane_u(send, u, lane);
                vlo[j] = isE ? keep : ex;
                vhi[j] = isE ? ex : keep;
            }
        } else {
            const float w1 = 1.0f - w0;
#pragma unroll
            for (int j = 0; j < 16; ++j) {
                float a = vlo[j], c = vhi[j];
                float oa = w0 * a + w1 * c;
                vlo[j] = oa;
                vhi[j] = a + c - oa;
            }
        }
    }

    // ---- store: reuse dead xb as 64-row f32 staging, two coalesced passes ---
    float* vbuf = (float*)smem;   // 64 rows x 128 f32 = 32KB (= xb region)
    const int FU = NS - 1;
    const int r0 = ((lane >> FU) << (FU + 1)) | (lane & ((1 << FU) - 1));
    const int r1 = r0 + (1 << FU);
    const int rl = tid >> 5, c4 = tid & 31;
#pragma unroll
    for (int pass = 0; pass < 2; ++pass) {
        if (pass) __syncthreads();   // prior pass's store-reads done
        if ((r0 >> 6) == pass) {
            const int lr = r0 & 63;
#pragma unroll
            for (int j = 0; j < 4; ++j) {
                float4 a; a.x = vlo[4*j]; a.y = vlo[4*j+1]; a.z = vlo[4*j+2]; a.w = vlo[4*j+3];
                *(float4*)(vbuf + lr * 128 + (((w * 4 + j) ^ (lr & 31)) << 2)) = a;
            }
        }
        if ((r1 >> 6) == pass) {
            const int lr = r1 & 63;
#pragma unroll
            for (int j = 0; j < 4; ++j) {
                float4 c; c.x = vhi[4*j]; c.y = vhi[4*j+1]; c.z = vhi[4*j+2]; c.w = vhi[4*j+3];
                *(float4*)(vbuf + lr * 128 + (((w * 4 + j) ^ (lr & 31)) << 2)) = c;
            }
        }
        __syncthreads();
#pragma unroll
        for (int j = 0; j < 4; ++j) {
            int i  = j * 16 + rl;            // local row in this pass
            int gr = pass * 64 + i;          // row in tile
            int gp = base + (gr >> 6) * h_off + (gr & 63) * rstride;
            ((float4*)vdst)[gp * 32 + c4] =
                *(const float4*)(vbuf + i * 128 + ((c4 ^ (i & 31)) << 2));
        }
    }
}

extern "C" void kernel_launch(void* const* d_in, const int* in_sizes, int n_in,
                              void* d_out, int out_size, void* d_ws, size_t ws_size,
                              hipStream_t stream) {
    const float* x   = (const float*)d_in[0];
    const float* qkw = (const float*)d_in[1];
    float* out = (float*)d_out;
    unsigned short* PT = (unsigned short*)d_ws;   // 13*16384 bf16 = 416 KB

    (void)hipFuncSetAttribute((const void*)prep_kernel,
                              hipFuncAttributeMaxDynamicSharedMemorySize, PREP_LDS);
    (void)hipFuncSetAttribute((const void*)fused_kernel<7>,
                              hipFuncAttributeMaxDynamicSharedMemorySize, LDS_FUSED);
    (void)hipFuncSetAttribute((const void*)fused_kernel<6>,
                              hipFuncAttributeMaxDynamicSharedMemorySize, LDS_FUSED);

    prep_kernel<<<13, 512, PREP_LDS, stream>>>(qkw, PT);

    // stages 0..6: contiguous 128-position blocks; v init = x
    fused_kernel<7><<<1024, 512, LDS_FUSED, stream>>>(
        x, x, out, PT, /*s0=*/0, /*base_mul=*/128, /*h_off=*/64, /*rstride=*/1);

    // stages 7..12: 2 lo x 64 hi (stride 128); in-place on d_out
    fused_kernel<6><<<1024, 512, LDS_FUSED, stream>>>(
        x, out, out, PT, /*s0=*/7, /*base_mul=*/2, /*h_off=*/1, /*rstride=*/128);
}